// Round 7
// baseline (1887.901 us; speedup 1.0000x reference)
//
#include <hip/hip_runtime.h>
#include <cstdint>
#include <cstddef>

#define TT 512
#define BB 64
#define HH 256
#define NG 1024
#define DI 768
#define KY 32

#define LDP 56   // kgemm2 LDS pitch (bf16 elems): 112B rows, 16B-aligned

typedef __attribute__((ext_vector_type(8))) short bfrag_t;
typedef __attribute__((ext_vector_type(4))) float f4_t;

__device__ __forceinline__ float sigf(float x) {
    return __fdividef(1.f, 1.f + __expf(-x));
}
__device__ __forceinline__ float tanhfast(float x) {
    return fmaf(2.f, sigf(2.f * x), -1.f);
}
__device__ __forceinline__ unsigned short bf_hi(float x) {
    return (unsigned short)(__float_as_uint(x) >> 16);
}
__device__ __forceinline__ float bf_hi_f(float x) {
    return __uint_as_float(__float_as_uint(x) & 0xffff0000u);
}

// ---------------------------------------------------------------------------
// kconvW: one-time split of Wih[:, 32:800] into bf16 hi/lo planes (3 MB).
// Removes the 256x-redundant per-block conversion from kgemm2.
// ---------------------------------------------------------------------------
__global__ __launch_bounds__(256) void kconvW(
    const float* __restrict__ Wih,
    unsigned short* __restrict__ WH, unsigned short* __restrict__ WL)
{
    const int col = blockIdx.x * 256 + threadIdx.x;   // 0..767
    const int row = blockIdx.y;                       // 0..1023
    float v = Wih[(size_t)row * 800 + KY + col];
    WH[(size_t)row * DI + col] = bf_hi(v);
    WL[(size_t)row * DI + col] = bf_hi(v - bf_hi_f(v));
}

// ---------------------------------------------------------------------------
// kgemm2: G_pre = A @ B^T + bias via split-bf16 MFMA (hh+hl+lh).
// B-side loads preconverted hi/lo planes (16B vector loads, no VALU).
// ---------------------------------------------------------------------------
__global__ __launch_bounds__(256) void kgemm2(
    const float* __restrict__ sents,
    const unsigned short* __restrict__ WH, const unsigned short* __restrict__ WL,
    const float* __restrict__ bih, const float* __restrict__ bhh,
    float* __restrict__ gpre, int t0)
{
    __shared__ __align__(16) unsigned short Ah[128 * LDP], Al[128 * LDP];
    __shared__ __align__(16) unsigned short Bh[128 * LDP], Bl[128 * LDP];

    const int tid = threadIdx.x;
    const int nb = blockIdx.x;
    const int mb = blockIdx.y;
    const int wv = tid >> 6, lane = tid & 63;
    const int wm = (wv >> 1) * 64, wn = (wv & 1) * 64;
    const int fl = lane & 15, quad = lane >> 4;

    f4_t acc[4][4];
#pragma unroll
    for (int mi = 0; mi < 4; ++mi)
#pragma unroll
        for (int ni = 0; ni < 4; ++ni) acc[mi][ni] = (f4_t)0.f;

    const int sr = tid >> 1, sk = (tid & 1) * 16;
    const int gr = mb * 128 + sr;
    const float* aptr = sents + ((size_t)(gr & 63) * TT + t0 + (gr >> 6)) * DI + sk;
    const unsigned short* bhp = WH + (size_t)(nb * 128 + sr) * DI + sk;
    const unsigned short* blp = WL + (size_t)(nb * 128 + sr) * DI + sk;

    for (int k0 = 0; k0 < DI; k0 += 32) {
        float4 av[4];
#pragma unroll
        for (int i = 0; i < 4; ++i) av[i] = *(const float4*)(aptr + k0 + i * 4);
        uint4 bh0 = *(const uint4*)(bhp + k0);
        uint4 bh1 = *(const uint4*)(bhp + k0 + 8);
        uint4 bl0 = *(const uint4*)(blp + k0);
        uint4 bl1 = *(const uint4*)(blp + k0 + 8);
        __syncthreads();
#pragma unroll
        for (int i = 0; i < 4; ++i) {
            ushort4 h4, l4;
            h4.x = bf_hi(av[i].x); l4.x = bf_hi(av[i].x - bf_hi_f(av[i].x));
            h4.y = bf_hi(av[i].y); l4.y = bf_hi(av[i].y - bf_hi_f(av[i].y));
            h4.z = bf_hi(av[i].z); l4.z = bf_hi(av[i].z - bf_hi_f(av[i].z));
            h4.w = bf_hi(av[i].w); l4.w = bf_hi(av[i].w - bf_hi_f(av[i].w));
            *(ushort4*)&Ah[sr * LDP + sk + i * 4] = h4;
            *(ushort4*)&Al[sr * LDP + sk + i * 4] = l4;
        }
        *(uint4*)&Bh[sr * LDP + sk + 0] = bh0;
        *(uint4*)&Bh[sr * LDP + sk + 8] = bh1;
        *(uint4*)&Bl[sr * LDP + sk + 0] = bl0;
        *(uint4*)&Bl[sr * LDP + sk + 8] = bl1;
        __syncthreads();

        bfrag_t ah[4], al2[4], bh[4], bl2[4];
#pragma unroll
        for (int mi = 0; mi < 4; ++mi) {
            int row = wm + mi * 16 + fl;
            ah[mi]  = *(const bfrag_t*)&Ah[row * LDP + quad * 8];
            al2[mi] = *(const bfrag_t*)&Al[row * LDP + quad * 8];
        }
#pragma unroll
        for (int ni = 0; ni < 4; ++ni) {
            int col = wn + ni * 16 + fl;
            bh[ni]  = *(const bfrag_t*)&Bh[col * LDP + quad * 8];
            bl2[ni] = *(const bfrag_t*)&Bl[col * LDP + quad * 8];
        }
#pragma unroll
        for (int mi = 0; mi < 4; ++mi)
#pragma unroll
            for (int ni = 0; ni < 4; ++ni) {
                acc[mi][ni] = __builtin_amdgcn_mfma_f32_16x16x32_bf16(
                    ah[mi], bh[ni], acc[mi][ni], 0, 0, 0);
                acc[mi][ni] = __builtin_amdgcn_mfma_f32_16x16x32_bf16(
                    ah[mi], bl2[ni], acc[mi][ni], 0, 0, 0);
                acc[mi][ni] = __builtin_amdgcn_mfma_f32_16x16x32_bf16(
                    al2[mi], bh[ni], acc[mi][ni], 0, 0, 0);
            }
    }

#pragma unroll
    for (int ni = 0; ni < 4; ++ni) {
        int gcol = nb * 128 + wn + ni * 16 + fl;
        float bias = bih[gcol] + bhh[gcol];
#pragma unroll
        for (int mi = 0; mi < 4; ++mi) {
            int grow = mb * 128 + wm + mi * 16 + quad * 4;
#pragma unroll
            for (int r = 0; r < 4; ++r)
                gpre[(size_t)(grow + r) * NG + gcol] = acc[mi][ni][r] + bias;
        }
    }
}

// ---------------------------------------------------------------------------
// Kernel S: SHi[tl][b][k] = sents[b][t0+tl][:] @ Waff[k][256:1024]^T + baff[k]
// ---------------------------------------------------------------------------
__global__ __launch_bounds__(256) void kshi(
    const float* __restrict__ sents, const float* __restrict__ Waff,
    const float* __restrict__ baff, float* __restrict__ shi, int t0)
{
    const int tid = threadIdx.x;
    const int lane = tid & 63;
    const int r = blockIdx.x * 4 + (tid >> 6);
    const int b = r & 63, tl = r >> 6;
    const float* hi = sents + ((size_t)b * TT + t0 + tl) * DI;
    float p0 = 0.f, p1 = 0.f;
#pragma unroll
    for (int kk = 0; kk < 12; ++kk) {
        int k = kk * 64 + lane;
        float x = hi[k];
        p0 = fmaf(x, Waff[HH + k], p0);
        p1 = fmaf(x, Waff[NG + HH + k], p1);
    }
#pragma unroll
    for (int off = 32; off >= 1; off >>= 1) {
        p0 += __shfl_xor(p0, off, 64);
        p1 += __shfl_xor(p1, off, 64);
    }
    if (lane == 0) {
        shi[(size_t)r * 2 + 0] = p0 + baff[0];
        shi[(size_t)r * 2 + 1] = p1 + baff[1];
    }
}

// ---------------------------------------------------------------------------
// init: zero the packed mailbox words (32768 u64)
// ---------------------------------------------------------------------------
__global__ void kinit(unsigned long long* __restrict__ hbox) {
    hbox[(size_t)blockIdx.x * 512 + threadIdx.x] = 0ull;
}

// ---------------------------------------------------------------------------
// krec5: krec3's exchange (hn-only packed words, relaxed agent atomics,
// parity double-buffer, exact-match counter) with TWO batch elements per WG.
// WG (g,bp) runs b0=bp and b1=bp+32 with the SAME register-resident Whh
// slice. b1's compute fills b0's mailbox RT; b1's RT is mostly elapsed by
// the time it's polled. One barrier after both polls; parallel epilogues.
// ---------------------------------------------------------------------------
__global__ __launch_bounds__(512, 1) void krec5(
    const float* __restrict__ gpre,   // [Tc][64][1024]
    const float* __restrict__ shi,    // [Tc][64][2]
    const float* __restrict__ Whh,    // [1024][256]
    const float* __restrict__ mask,   // [64][512]
    float* __restrict__ out,          // [64][512][2]
    float* __restrict__ sh, float* __restrict__ sc, int* __restrict__ sp,
    unsigned long long* __restrict__ hbox,  // [2][64][4][64]
    const float* __restrict__ Wih, const float* __restrict__ tag,
    const float* __restrict__ Waff,
    int t0, int Tc, int first)
{
    const int blk = blockIdx.x;
    const int g = blk >> 5, bp = blk & 31;
    const int b0 = bp, b1 = bp + 32;
    const int tid = threadIdx.x;
    const int w = tid >> 6, lane = tid & 63;
    const int jl = lane & 7, kq = lane >> 3;
    const int jh = w * 8 + jl;
    const int jglob = g * 64 + jh;

    __shared__ float hk0[8 * 36], hk1[8 * 36];
    __shared__ float hnS0[HH], hnS1[HH];
    __shared__ float P[2][4][64];
    __shared__ float tg[2][KY];
    __shared__ float red0[8][2], red1[8][2];

    float4 wreg[4][8];
#pragma unroll
    for (int gt = 0; gt < 4; ++gt) {
        const float4* src = (const float4*)(Whh + (size_t)(gt * HH + jglob) * HH + kq * 32);
#pragma unroll
        for (int kk = 0; kk < 8; ++kk) wreg[gt][kk] = src[kk];
    }

    const int sdim = w * 32 + (lane & 31);
    const int stag = lane >> 5;
    const float waffR = Waff[(size_t)stag * NG + sdim];

    if (tid < 2 * KY) tg[tid >> 5][tid & 31] = tag[tid];
    __syncthreads();
    {   // P[r][gt][j2] = tag_em[r] @ Wih[gt*256 + 64g + j2][0:32]^T
        int r = tid >> 8, rem = tid & 255, gt = rem >> 6, j2 = rem & 63;
        int row = gt * HH + g * 64 + j2;
        const float4* wr = (const float4*)(Wih + (size_t)row * 800);
        float s = 0.f;
#pragma unroll
        for (int kk = 0; kk < 8; ++kk) {
            float4 v = wr[kk];
            s = fmaf(v.x, tg[r][kk * 4 + 0], s);
            s = fmaf(v.y, tg[r][kk * 4 + 1], s);
            s = fmaf(v.z, tg[r][kk * 4 + 2], s);
            s = fmaf(v.w, tg[r][kk * 4 + 3], s);
        }
        P[r][gt][j2] = s;
    }

    float creg0, creg1; int pred0, pred1;
    if (first) {
        creg0 = 0.f; creg1 = 0.f; pred0 = -1; pred1 = -1;
        if (tid < HH) {
            hk0[(tid >> 5) * 36 + (tid & 31)] = 0.f;
            hk1[(tid >> 5) * 36 + (tid & 31)] = 0.f;
        }
    } else {
        creg0 = sc[(size_t)b0 * HH + jglob];
        creg1 = sc[(size_t)b1 * HH + jglob];
        pred0 = sp[b0]; pred1 = sp[b1];
        if (tid < HH) {
            hk0[(tid >> 5) * 36 + (tid & 31)] = sh[(size_t)b0 * HH + tid];
            hk1[(tid >> 5) * 36 + (tid & 31)] = sh[(size_t)b1 * HH + tid];
        }
    }
    __syncthreads();

    // prefetched current-step operands for both batch elements
    float cgp00, cgp01, cgp02, cgp03, cmi0, cs00, cs01;
    float cgp10, cgp11, cgp12, cgp13, cmi1, cs10, cs11;
    {
        const float* gpa = gpre + (size_t)b0 * NG;
        cgp00 = gpa[0 * HH + jglob]; cgp01 = gpa[1 * HH + jglob];
        cgp02 = gpa[2 * HH + jglob]; cgp03 = gpa[3 * HH + jglob];
        cmi0 = mask[(size_t)b0 * TT + t0];
        const float* s2a = shi + (size_t)b0 * 2;
        cs00 = s2a[0]; cs01 = s2a[1];
        const float* gpb = gpre + (size_t)b1 * NG;
        cgp10 = gpb[0 * HH + jglob]; cgp11 = gpb[1 * HH + jglob];
        cgp12 = gpb[2 * HH + jglob]; cgp13 = gpb[3 * HH + jglob];
        cmi1 = mask[(size_t)b1 * TT + t0];
        const float* s2b = shi + (size_t)b1 * 2;
        cs10 = s2b[0]; cs11 = s2b[1];
    }

    for (int tl = 0; tl < Tc; ++tl) {
        const int t = t0 + tl;
        const int p = t & 1;
        const unsigned cnt = (unsigned)(t + 1);

        // =================== b0: matvec + gates + publish ===================
        float pv0 = 0.f, pv1 = 0.f, pv2 = 0.f, pv3 = 0.f;
        if (pred0 >= 0) {
            pv0 = P[pred0][0][jh]; pv1 = P[pred0][1][jh];
            pv2 = P[pred0][2][jh]; pv3 = P[pred0][3][jh];
        }
        float a0 = 0.f, a1 = 0.f, a2 = 0.f, a3 = 0.f;
        {
            const float4* h4 = (const float4*)(hk0 + kq * 36);
#pragma unroll
            for (int kk = 0; kk < 8; ++kk) {
                float4 hv = h4[kk];
                a0 = fmaf(wreg[0][kk].x, hv.x, a0); a0 = fmaf(wreg[0][kk].y, hv.y, a0);
                a0 = fmaf(wreg[0][kk].z, hv.z, a0); a0 = fmaf(wreg[0][kk].w, hv.w, a0);
                a1 = fmaf(wreg[1][kk].x, hv.x, a1); a1 = fmaf(wreg[1][kk].y, hv.y, a1);
                a1 = fmaf(wreg[1][kk].z, hv.z, a1); a1 = fmaf(wreg[1][kk].w, hv.w, a1);
                a2 = fmaf(wreg[2][kk].x, hv.x, a2); a2 = fmaf(wreg[2][kk].y, hv.y, a2);
                a2 = fmaf(wreg[2][kk].z, hv.z, a2); a2 = fmaf(wreg[2][kk].w, hv.w, a2);
                a3 = fmaf(wreg[3][kk].x, hv.x, a3); a3 = fmaf(wreg[3][kk].y, hv.y, a3);
                a3 = fmaf(wreg[3][kk].z, hv.z, a3); a3 = fmaf(wreg[3][kk].w, hv.w, a3);
            }
        }
        a0 += __shfl_xor(a0, 8, 64); a0 += __shfl_xor(a0, 16, 64); a0 += __shfl_xor(a0, 32, 64);
        a1 += __shfl_xor(a1, 8, 64); a1 += __shfl_xor(a1, 16, 64); a1 += __shfl_xor(a1, 32, 64);
        a2 += __shfl_xor(a2, 8, 64); a2 += __shfl_xor(a2, 16, 64); a2 += __shfl_xor(a2, 32, 64);
        a3 += __shfl_xor(a3, 8, 64); a3 += __shfl_xor(a3, 16, 64); a3 += __shfl_xor(a3, 32, 64);

        const float mi0 = cmi0, sv00 = cs00, sv01 = cs01;
        float hn0;
        {
            float gi = a0 + cgp00 + pv0;
            float gf = a1 + cgp01 + pv1;
            float gg = a2 + cgp02 + pv2;
            float go = a3 + cgp03 + pv3;
            float ig = sigf(gi), fg = sigf(gf);
            float g2 = tanhfast(gg), og = sigf(go);
            float cn = fmaf(fg, creg0, ig * g2);
            hn0 = og * tanhfast(cn);
            creg0 = cn * mi0 + creg0 * (1.f - mi0);
        }
        if (kq == 0) {
            unsigned long long wd =
                ((unsigned long long)__float_as_uint(hn0) << 32) | cnt;
            __hip_atomic_store(&hbox[((size_t)(p * BB + b0) * 4 + g) * 64 + jh], wd,
                               __ATOMIC_RELAXED, __HIP_MEMORY_SCOPE_AGENT);
            hnS0[jglob] = hn0;
        }

        // =================== b1: matvec + gates + publish ===================
        float qv0 = 0.f, qv1 = 0.f, qv2 = 0.f, qv3 = 0.f;
        if (pred1 >= 0) {
            qv0 = P[pred1][0][jh]; qv1 = P[pred1][1][jh];
            qv2 = P[pred1][2][jh]; qv3 = P[pred1][3][jh];
        }
        float e0 = 0.f, e1 = 0.f, e2 = 0.f, e3 = 0.f;
        {
            const float4* h4 = (const float4*)(hk1 + kq * 36);
#pragma unroll
            for (int kk = 0; kk < 8; ++kk) {
                float4 hv = h4[kk];
                e0 = fmaf(wreg[0][kk].x, hv.x, e0); e0 = fmaf(wreg[0][kk].y, hv.y, e0);
                e0 = fmaf(wreg[0][kk].z, hv.z, e0); e0 = fmaf(wreg[0][kk].w, hv.w, e0);
                e1 = fmaf(wreg[1][kk].x, hv.x, e1); e1 = fmaf(wreg[1][kk].y, hv.y, e1);
                e1 = fmaf(wreg[1][kk].z, hv.z, e1); e1 = fmaf(wreg[1][kk].w, hv.w, e1);
                e2 = fmaf(wreg[2][kk].x, hv.x, e2); e2 = fmaf(wreg[2][kk].y, hv.y, e2);
                e2 = fmaf(wreg[2][kk].z, hv.z, e2); e2 = fmaf(wreg[2][kk].w, hv.w, e2);
                e3 = fmaf(wreg[3][kk].x, hv.x, e3); e3 = fmaf(wreg[3][kk].y, hv.y, e3);
                e3 = fmaf(wreg[3][kk].z, hv.z, e3); e3 = fmaf(wreg[3][kk].w, hv.w, e3);
            }
        }
        e0 += __shfl_xor(e0, 8, 64); e0 += __shfl_xor(e0, 16, 64); e0 += __shfl_xor(e0, 32, 64);
        e1 += __shfl_xor(e1, 8, 64); e1 += __shfl_xor(e1, 16, 64); e1 += __shfl_xor(e1, 32, 64);
        e2 += __shfl_xor(e2, 8, 64); e2 += __shfl_xor(e2, 16, 64); e2 += __shfl_xor(e2, 32, 64);
        e3 += __shfl_xor(e3, 8, 64); e3 += __shfl_xor(e3, 16, 64); e3 += __shfl_xor(e3, 32, 64);

        const float mi1 = cmi1, sv10 = cs10, sv11 = cs11;
        float hn1;
        {
            float gi = e0 + cgp10 + qv0;
            float gf = e1 + cgp11 + qv1;
            float gg = e2 + cgp12 + qv2;
            float go = e3 + cgp13 + qv3;
            float ig = sigf(gi), fg = sigf(gf);
            float g2 = tanhfast(gg), og = sigf(go);
            float cn = fmaf(fg, creg1, ig * g2);
            hn1 = og * tanhfast(cn);
            creg1 = cn * mi1 + creg1 * (1.f - mi1);
        }
        if (kq == 0) {
            unsigned long long wd =
                ((unsigned long long)__float_as_uint(hn1) << 32) | cnt;
            __hip_atomic_store(&hbox[((size_t)(p * BB + b1) * 4 + g) * 64 + jh], wd,
                               __ATOMIC_RELAXED, __HIP_MEMORY_SCOPE_AGENT);
            hnS1[jglob] = hn1;
        }

        // ---- prefetch next step's operands (hidden under the polls) ----
        if (tl + 1 < Tc) {
            const float* gpa = gpre + ((size_t)(tl + 1) * BB + b0) * NG;
            cgp00 = gpa[0 * HH + jglob]; cgp01 = gpa[1 * HH + jglob];
            cgp02 = gpa[2 * HH + jglob]; cgp03 = gpa[3 * HH + jglob];
            cmi0 = mask[(size_t)b0 * TT + t + 1];
            const float* s2a = shi + ((size_t)(tl + 1) * BB + b0) * 2;
            cs00 = s2a[0]; cs01 = s2a[1];
            const float* gpb = gpre + ((size_t)(tl + 1) * BB + b1) * NG;
            cgp10 = gpb[0 * HH + jglob]; cgp11 = gpb[1 * HH + jglob];
            cgp12 = gpb[2 * HH + jglob]; cgp13 = gpb[3 * HH + jglob];
            cmi1 = mask[(size_t)b1 * TT + t + 1];
            const float* s2b = shi + ((size_t)(tl + 1) * BB + b1) * 2;
            cs10 = s2b[0]; cs11 = s2b[1];
        }

        // ---- poll partner slices: b0 then b1 ----
        if (tid < 192) {
            int pg = (g + 1 + (tid >> 6)) & 3, j2 = tid & 63;
            {
                const unsigned long long* wp =
                    &hbox[((size_t)(p * BB + b0) * 4 + pg) * 64 + j2];
                unsigned long long wv;
                do {
                    wv = __hip_atomic_load(wp, __ATOMIC_RELAXED, __HIP_MEMORY_SCOPE_AGENT);
                } while ((unsigned)wv != cnt);
                hnS0[pg * 64 + j2] = __uint_as_float((unsigned)(wv >> 32));
            }
            {
                const unsigned long long* wp =
                    &hbox[((size_t)(p * BB + b1) * 4 + pg) * 64 + j2];
                unsigned long long wv;
                do {
                    wv = __hip_atomic_load(wp, __ATOMIC_RELAXED, __HIP_MEMORY_SCOPE_AGENT);
                } while ((unsigned)wv != cnt);
                hnS1[pg * 64 + j2] = __uint_as_float((unsigned)(wv >> 32));
            }
        }
        __syncthreads();   // B3: hnS0/hnS1 complete; hk reads of this step done

        // ---- parallel h_out updates: threads 0-255 -> b0, 256-511 -> b1 ----
        if (tid < HH) {
            int idx = (tid >> 5) * 36 + (tid & 31);
            float hold = hk0[idx];
            hk0[idx] = hnS0[tid] * mi0 + hold * (1.f - mi0);
        } else {
            int d = tid - HH;
            int idx = (d >> 5) * 36 + (d & 31);
            float hold = hk1[idx];
            hk1[idx] = hnS1[d] * mi1 + hold * (1.f - mi1);
        }
        // ---- score recompute (fixed order, bit-identical in all 4 WGs) ----
        float pr0 = hnS0[sdim] * waffR;
        pr0 += __shfl_xor(pr0, 1, 64);
        pr0 += __shfl_xor(pr0, 2, 64);
        pr0 += __shfl_xor(pr0, 4, 64);
        pr0 += __shfl_xor(pr0, 8, 64);
        pr0 += __shfl_xor(pr0, 16, 64);
        float pr1 = hnS1[sdim] * waffR;
        pr1 += __shfl_xor(pr1, 1, 64);
        pr1 += __shfl_xor(pr1, 2, 64);
        pr1 += __shfl_xor(pr1, 4, 64);
        pr1 += __shfl_xor(pr1, 8, 64);
        pr1 += __shfl_xor(pr1, 16, 64);
        if ((lane & 31) == 0) {
            red0[w][stag] = pr0;
            red1[w][stag] = pr1;
        }
        __syncthreads();   // B4: red + hk complete

        {
            float s0 = red0[0][0];
            s0 += red0[1][0]; s0 += red0[2][0]; s0 += red0[3][0];
            s0 += red0[4][0]; s0 += red0[5][0]; s0 += red0[6][0]; s0 += red0[7][0];
            float s1 = red0[0][1];
            s1 += red0[1][1]; s1 += red0[2][1]; s1 += red0[3][1];
            s1 += red0[4][1]; s1 += red0[5][1]; s1 += red0[6][1]; s1 += red0[7][1];
            float ts0 = s0 + sv00, ts1 = s1 + sv01;
            pred0 = (ts1 > ts0) ? 1 : 0;
            if (g == 0 && tid == 0) {
                float m = fmaxf(ts0, ts1);
                float lse = m + log1pf(expf(-fabsf(ts0 - ts1)));
                float* op = out + ((size_t)b0 * TT + t) * 2;
                op[0] = ts0 - lse; op[1] = ts1 - lse;
            }
        }
        {
            float s0 = red1[0][0];
            s0 += red1[1][0]; s0 += red1[2][0]; s0 += red1[3][0];
            s0 += red1[4][0]; s0 += red1[5][0]; s0 += red1[6][0]; s0 += red1[7][0];
            float s1 = red1[0][1];
            s1 += red1[1][1]; s1 += red1[2][1]; s1 += red1[3][1];
            s1 += red1[4][1]; s1 += red1[5][1]; s1 += red1[6][1]; s1 += red1[7][1];
            float ts0 = s0 + sv10, ts1 = s1 + sv11;
            pred1 = (ts1 > ts0) ? 1 : 0;
            if (g == 0 && tid == 0) {
                float m = fmaxf(ts0, ts1);
                float lse = m + log1pf(expf(-fabsf(ts0 - ts1)));
                float* op = out + ((size_t)b1 * TT + t) * 2;
                op[0] = ts0 - lse; op[1] = ts1 - lse;
            }
        }
    }

    if (kq == 0) {
        sh[(size_t)b0 * HH + jglob] = hk0[(jglob >> 5) * 36 + (jglob & 31)];
        sc[(size_t)b0 * HH + jglob] = creg0;
        sh[(size_t)b1 * HH + jglob] = hk1[(jglob >> 5) * 36 + (jglob & 31)];
        sc[(size_t)b1 * HH + jglob] = creg1;
    }
    if (g == 0 && tid == 0) { sp[b0] = pred0; sp[b1] = pred1; }
}

// ---------------------------------------------------------------------------
extern "C" void kernel_launch(void* const* d_in, const int* in_sizes, int n_in,
                              void* d_out, int out_size, void* d_ws, size_t ws_size,
                              hipStream_t stream) {
    (void)in_sizes; (void)n_in; (void)out_size;
    const float* sents = (const float*)d_in[0];
    const float* mask  = (const float*)d_in[1];
    const float* Wih   = (const float*)d_in[2];
    const float* Whh   = (const float*)d_in[3];
    const float* bih   = (const float*)d_in[4];
    const float* bhh   = (const float*)d_in[5];
    const float* Waff  = (const float*)d_in[6];
    const float* baff  = (const float*)d_in[7];
    const float* tag   = (const float*)d_in[8];
    float* out = (float*)d_out;

    const size_t wsplit = (size_t)NG * DI * 2 * 2;        // WH + WL (3 MB)
    const size_t fixed = wsplit
                       + (size_t)BB * HH * 4 * 2          // sh, sc
                       + BB * 4                            // sp
                       + (size_t)2 * BB * 4 * 64 * 8      // hbox
                       + 4096;
    int Tc = 8;
    const int cands[7] = {512, 256, 128, 64, 32, 16, 8};
    for (int i = 0; i < 7; ++i) {
        size_t need = (size_t)cands[i] * BB * NG * 4
                    + (size_t)cands[i] * BB * 2 * 4
                    + fixed;
        if (need <= ws_size) { Tc = cands[i]; break; }
    }

    char* wsp = (char*)d_ws;
    unsigned short* WH = (unsigned short*)wsp; wsp += (size_t)NG * DI * 2;
    unsigned short* WL = (unsigned short*)wsp; wsp += (size_t)NG * DI * 2;
    float* gpre = (float*)wsp; wsp += (size_t)Tc * BB * NG * 4;
    float* shiw = (float*)wsp; wsp += (size_t)Tc * BB * 2 * 4;
    float* shst = (float*)wsp; wsp += (size_t)BB * HH * 4;
    float* scst = (float*)wsp; wsp += (size_t)BB * HH * 4;
    int*   spst = (int*)wsp;   wsp += BB * 4;
    unsigned long long* hbox = (unsigned long long*)wsp;

    kconvW<<<dim3(3, 1024), 256, 0, stream>>>(Wih, WH, WL);
    kinit<<<dim3(64), 512, 0, stream>>>(hbox);

    const int nch = TT / Tc;
    for (int c = 0; c < nch; ++c) {
        const int t0 = c * Tc;
        kgemm2<<<dim3(8, Tc * 64 / 128), 256, 0, stream>>>(sents, WH, WL, bih, bhh, gpre, t0);
        kshi<<<dim3(Tc * 16), 256, 0, stream>>>(sents, Waff, baff, shiw, t0);
        krec5<<<dim3(128), 512, 0, stream>>>(gpre, shiw, Whh, mask, out,
                                             shst, scst, spst, hbox,
                                             Wih, tag, Waff, t0, Tc, (c == 0) ? 1 : 0);
    }
}

// Round 8
// 1708.702 us; speedup vs baseline: 1.1049x; 1.1049x over previous
//
#include <hip/hip_runtime.h>
#include <cstdint>
#include <cstddef>

#define TT 512
#define BB 64
#define HH 256
#define NG 1024
#define DI 768
#define KY 32

#define LDP 56   // kgemm2 LDS pitch (bf16 elems): 112B rows, 16B-aligned

typedef __attribute__((ext_vector_type(8))) short bfrag_t;
typedef __attribute__((ext_vector_type(4))) float f4_t;

__device__ __forceinline__ float sigf(float x) {
    return __fdividef(1.f, 1.f + __expf(-x));
}
__device__ __forceinline__ float tanhfast(float x) {
    return fmaf(2.f, sigf(2.f * x), -1.f);
}
__device__ __forceinline__ unsigned short bf_hi(float x) {
    return (unsigned short)(__float_as_uint(x) >> 16);
}
__device__ __forceinline__ float bf_hi_f(float x) {
    return __uint_as_float(__float_as_uint(x) & 0xffff0000u);
}

// ---------------------------------------------------------------------------
// kconvW: one-time split of Wih[:, 32:800] into bf16 hi/lo planes (3 MB).
// ---------------------------------------------------------------------------
__global__ __launch_bounds__(256) void kconvW(
    const float* __restrict__ Wih,
    unsigned short* __restrict__ WH, unsigned short* __restrict__ WL)
{
    const int col = blockIdx.x * 256 + threadIdx.x;   // 0..767
    const int row = blockIdx.y;                       // 0..1023
    float v = Wih[(size_t)row * 800 + KY + col];
    WH[(size_t)row * DI + col] = bf_hi(v);
    WL[(size_t)row * DI + col] = bf_hi(v - bf_hi_f(v));
}

// ---------------------------------------------------------------------------
// kgemm2: G_pre = A @ B^T + bias via split-bf16 MFMA (hh+hl+lh).
// ---------------------------------------------------------------------------
__global__ __launch_bounds__(256) void kgemm2(
    const float* __restrict__ sents,
    const unsigned short* __restrict__ WH, const unsigned short* __restrict__ WL,
    const float* __restrict__ bih, const float* __restrict__ bhh,
    float* __restrict__ gpre, int t0)
{
    __shared__ __align__(16) unsigned short Ah[128 * LDP], Al[128 * LDP];
    __shared__ __align__(16) unsigned short Bh[128 * LDP], Bl[128 * LDP];

    const int tid = threadIdx.x;
    const int nb = blockIdx.x;
    const int mb = blockIdx.y;
    const int wv = tid >> 6, lane = tid & 63;
    const int wm = (wv >> 1) * 64, wn = (wv & 1) * 64;
    const int fl = lane & 15, quad = lane >> 4;

    f4_t acc[4][4];
#pragma unroll
    for (int mi = 0; mi < 4; ++mi)
#pragma unroll
        for (int ni = 0; ni < 4; ++ni) acc[mi][ni] = (f4_t)0.f;

    const int sr = tid >> 1, sk = (tid & 1) * 16;
    const int gr = mb * 128 + sr;
    const float* aptr = sents + ((size_t)(gr & 63) * TT + t0 + (gr >> 6)) * DI + sk;
    const unsigned short* bhp = WH + (size_t)(nb * 128 + sr) * DI + sk;
    const unsigned short* blp = WL + (size_t)(nb * 128 + sr) * DI + sk;

    for (int k0 = 0; k0 < DI; k0 += 32) {
        float4 av[4];
#pragma unroll
        for (int i = 0; i < 4; ++i) av[i] = *(const float4*)(aptr + k0 + i * 4);
        uint4 bh0 = *(const uint4*)(bhp + k0);
        uint4 bh1 = *(const uint4*)(bhp + k0 + 8);
        uint4 bl0 = *(const uint4*)(blp + k0);
        uint4 bl1 = *(const uint4*)(blp + k0 + 8);
        __syncthreads();
#pragma unroll
        for (int i = 0; i < 4; ++i) {
            ushort4 h4, l4;
            h4.x = bf_hi(av[i].x); l4.x = bf_hi(av[i].x - bf_hi_f(av[i].x));
            h4.y = bf_hi(av[i].y); l4.y = bf_hi(av[i].y - bf_hi_f(av[i].y));
            h4.z = bf_hi(av[i].z); l4.z = bf_hi(av[i].z - bf_hi_f(av[i].z));
            h4.w = bf_hi(av[i].w); l4.w = bf_hi(av[i].w - bf_hi_f(av[i].w));
            *(ushort4*)&Ah[sr * LDP + sk + i * 4] = h4;
            *(ushort4*)&Al[sr * LDP + sk + i * 4] = l4;
        }
        *(uint4*)&Bh[sr * LDP + sk + 0] = bh0;
        *(uint4*)&Bh[sr * LDP + sk + 8] = bh1;
        *(uint4*)&Bl[sr * LDP + sk + 0] = bl0;
        *(uint4*)&Bl[sr * LDP + sk + 8] = bl1;
        __syncthreads();

        bfrag_t ah[4], al2[4], bh[4], bl2[4];
#pragma unroll
        for (int mi = 0; mi < 4; ++mi) {
            int row = wm + mi * 16 + fl;
            ah[mi]  = *(const bfrag_t*)&Ah[row * LDP + quad * 8];
            al2[mi] = *(const bfrag_t*)&Al[row * LDP + quad * 8];
        }
#pragma unroll
        for (int ni = 0; ni < 4; ++ni) {
            int col = wn + ni * 16 + fl;
            bh[ni]  = *(const bfrag_t*)&Bh[col * LDP + quad * 8];
            bl2[ni] = *(const bfrag_t*)&Bl[col * LDP + quad * 8];
        }
#pragma unroll
        for (int mi = 0; mi < 4; ++mi)
#pragma unroll
            for (int ni = 0; ni < 4; ++ni) {
                acc[mi][ni] = __builtin_amdgcn_mfma_f32_16x16x32_bf16(
                    ah[mi], bh[ni], acc[mi][ni], 0, 0, 0);
                acc[mi][ni] = __builtin_amdgcn_mfma_f32_16x16x32_bf16(
                    ah[mi], bl2[ni], acc[mi][ni], 0, 0, 0);
                acc[mi][ni] = __builtin_amdgcn_mfma_f32_16x16x32_bf16(
                    al2[mi], bh[ni], acc[mi][ni], 0, 0, 0);
            }
    }

#pragma unroll
    for (int ni = 0; ni < 4; ++ni) {
        int gcol = nb * 128 + wn + ni * 16 + fl;
        float bias = bih[gcol] + bhh[gcol];
#pragma unroll
        for (int mi = 0; mi < 4; ++mi) {
            int grow = mb * 128 + wm + mi * 16 + quad * 4;
#pragma unroll
            for (int r = 0; r < 4; ++r)
                gpre[(size_t)(grow + r) * NG + gcol] = acc[mi][ni][r] + bias;
        }
    }
}

// ---------------------------------------------------------------------------
// Kernel S: SHi[tl][b][k] = sents[b][t0+tl][:] @ Waff[k][256:1024]^T + baff[k]
// ---------------------------------------------------------------------------
__global__ __launch_bounds__(256) void kshi(
    const float* __restrict__ sents, const float* __restrict__ Waff,
    const float* __restrict__ baff, float* __restrict__ shi, int t0)
{
    const int tid = threadIdx.x;
    const int lane = tid & 63;
    const int r = blockIdx.x * 4 + (tid >> 6);
    const int b = r & 63, tl = r >> 6;
    const float* hi = sents + ((size_t)b * TT + t0 + tl) * DI;
    float p0 = 0.f, p1 = 0.f;
#pragma unroll
    for (int kk = 0; kk < 12; ++kk) {
        int k = kk * 64 + lane;
        float x = hi[k];
        p0 = fmaf(x, Waff[HH + k], p0);
        p1 = fmaf(x, Waff[NG + HH + k], p1);
    }
#pragma unroll
    for (int off = 32; off >= 1; off >>= 1) {
        p0 += __shfl_xor(p0, off, 64);
        p1 += __shfl_xor(p1, off, 64);
    }
    if (lane == 0) {
        shi[(size_t)r * 2 + 0] = p0 + baff[0];
        shi[(size_t)r * 2 + 1] = p1 + baff[1];
    }
}

// ---------------------------------------------------------------------------
// init: zero the packed mailbox words (32768 u64)
// ---------------------------------------------------------------------------
__global__ void kinit(unsigned long long* __restrict__ hbox) {
    hbox[(size_t)blockIdx.x * 512 + threadIdx.x] = 0ull;
}

// ---------------------------------------------------------------------------
// krec6: 4-way-split recurrence; one barrier per step, no post-exchange
// epilogue on the critical path.
//  - h state in registers (hoct = this thread's K-octant); mix from hnS at
//    iteration top.
//  - score for step t-1: LDS partials (step-tagged u64) written at top,
//    tag-checked spin-sum AFTER the matvec -> pred resolves one iteration
//    late, fully overlapped. Same fixed sum order in all 4 WGs over
//    bit-identical hnS -> bit-identical pred, no cross-WG score traffic.
//  - hn exchange = krec3 protocol: packed (f32<<32|t+1) words, relaxed
//    agent atomics, parity double-buffer, exact-tag match.
// ---------------------------------------------------------------------------
__global__ __launch_bounds__(512, 1) void krec6(
    const float* __restrict__ gpre,   // [Tc][64][1024]
    const float* __restrict__ shi,    // [Tc][64][2]
    const float* __restrict__ Whh,    // [1024][256]
    const float* __restrict__ mask,   // [64][512]
    float* __restrict__ out,          // [64][512][2]
    float* __restrict__ sh, float* __restrict__ sc, int* __restrict__ sp,
    unsigned long long* __restrict__ hbox,  // [2][64][4][64]
    const float* __restrict__ Wih, const float* __restrict__ tag,
    const float* __restrict__ Waff,
    int t0, int Tc, int first)
{
    const int blk = blockIdx.x;
    const int g = blk >> 6, b = blk & 63;
    const int tid = threadIdx.x;
    const int w = tid >> 6, lane = tid & 63;
    const int jl = lane & 7, kq = lane >> 3;
    const int jh = w * 8 + jl;
    const int jglob = g * 64 + jh;

    __shared__ float hnS[2][HH];              // pre-mask hn, parity dbuf
    __shared__ unsigned long long redL[8][2]; // packed f32<<32 | tag
    __shared__ float P[2][4][64];
    __shared__ float tg[2][KY];

    float4 wreg[4][8];
#pragma unroll
    for (int gt = 0; gt < 4; ++gt) {
        const float4* src = (const float4*)(Whh + (size_t)(gt * HH + jglob) * HH + kq * 32);
#pragma unroll
        for (int kk = 0; kk < 8; ++kk) wreg[gt][kk] = src[kk];
    }

    const int sdim = w * 32 + (lane & 31);
    const int stag = lane >> 5;
    const float waffR = Waff[(size_t)stag * NG + sdim];

    if (tid < 2 * KY) tg[tid >> 5][tid & 31] = tag[tid];
    if (tid < 16) ((unsigned long long*)redL)[tid] = 0ull;
    __syncthreads();
    {   // P[r][gt][j2] = tag_em[r] @ Wih[gt*256 + 64g + j2][0:32]^T
        int r = tid >> 8, rem = tid & 255, gt = rem >> 6, j2 = rem & 63;
        int row = gt * HH + g * 64 + j2;
        const float4* wr = (const float4*)(Wih + (size_t)row * 800);
        float s = 0.f;
#pragma unroll
        for (int kk = 0; kk < 8; ++kk) {
            float4 v = wr[kk];
            s = fmaf(v.x, tg[r][kk * 4 + 0], s);
            s = fmaf(v.y, tg[r][kk * 4 + 1], s);
            s = fmaf(v.z, tg[r][kk * 4 + 2], s);
            s = fmaf(v.w, tg[r][kk * 4 + 3], s);
        }
        P[r][gt][j2] = s;
    }

    float creg; int pred;
    float4 hoct[8];                // h[32kq .. 32kq+32) post-mask state
    if (first) {
        creg = 0.f; pred = -1;
#pragma unroll
        for (int i = 0; i < 8; ++i) hoct[i] = make_float4(0.f, 0.f, 0.f, 0.f);
    } else {
        creg = sc[(size_t)b * HH + jglob];
        pred = sp[b];
        const float4* hs = (const float4*)(sh + (size_t)b * HH + kq * 32);
#pragma unroll
        for (int i = 0; i < 8; ++i) hoct[i] = hs[i];
    }
    __syncthreads();   // P, tg, redL init visible

    // current-step operands (prefetched); psv/pmi carry previous-step values
    float cgp0, cgp1, cgp2, cgp3, cmi, cs0, cs1;
    float pmi = 0.f, psv0 = 0.f, psv1 = 0.f;
    {
        const float* gp = gpre + (size_t)b * NG;
        cgp0 = gp[0 * HH + jglob]; cgp1 = gp[1 * HH + jglob];
        cgp2 = gp[2 * HH + jglob]; cgp3 = gp[3 * HH + jglob];
        cmi = mask[(size_t)b * TT + t0];
        const float* s2 = shi + (size_t)b * 2;
        cs0 = s2[0]; cs1 = s2[1];
    }

    for (int tl = 0; tl < Tc; ++tl) {
        const int t = t0 + tl;
        const int p = t & 1;
        const unsigned cnt = (unsigned)(t + 1);

        if (tl > 0) {
            // ---- mix: fold step t-1's hn into register h state ----
            const float4* hp = (const float4*)(&hnS[p ^ 1][kq * 32]);
#pragma unroll
            for (int i = 0; i < 8; ++i) {
                float4 hv = hp[i];
                hoct[i].x = hv.x * pmi + hoct[i].x * (1.f - pmi);
                hoct[i].y = hv.y * pmi + hoct[i].y * (1.f - pmi);
                hoct[i].z = hv.z * pmi + hoct[i].z * (1.f - pmi);
                hoct[i].w = hv.w * pmi + hoct[i].w * (1.f - pmi);
            }
            // ---- score partial for step t-1 (tagged write, summed later) ----
            float pr = hnS[p ^ 1][sdim] * waffR;
            pr += __shfl_xor(pr, 1, 64);
            pr += __shfl_xor(pr, 2, 64);
            pr += __shfl_xor(pr, 4, 64);
            pr += __shfl_xor(pr, 8, 64);
            pr += __shfl_xor(pr, 16, 64);
            if ((lane & 31) == 0) {
                unsigned long long wd =
                    ((unsigned long long)__float_as_uint(pr) << 32) | cnt;
                __hip_atomic_store(&redL[w][stag], wd,
                                   __ATOMIC_RELAXED, __HIP_MEMORY_SCOPE_WORKGROUP);
            }
        }

        // ---- matvec from registers ----
        float a0 = 0.f, a1 = 0.f, a2 = 0.f, a3 = 0.f;
#pragma unroll
        for (int kk = 0; kk < 8; ++kk) {
            float4 hv = hoct[kk];
            a0 = fmaf(wreg[0][kk].x, hv.x, a0); a0 = fmaf(wreg[0][kk].y, hv.y, a0);
            a0 = fmaf(wreg[0][kk].z, hv.z, a0); a0 = fmaf(wreg[0][kk].w, hv.w, a0);
            a1 = fmaf(wreg[1][kk].x, hv.x, a1); a1 = fmaf(wreg[1][kk].y, hv.y, a1);
            a1 = fmaf(wreg[1][kk].z, hv.z, a1); a1 = fmaf(wreg[1][kk].w, hv.w, a1);
            a2 = fmaf(wreg[2][kk].x, hv.x, a2); a2 = fmaf(wreg[2][kk].y, hv.y, a2);
            a2 = fmaf(wreg[2][kk].z, hv.z, a2); a2 = fmaf(wreg[2][kk].w, hv.w, a2);
            a3 = fmaf(wreg[3][kk].x, hv.x, a3); a3 = fmaf(wreg[3][kk].y, hv.y, a3);
            a3 = fmaf(wreg[3][kk].z, hv.z, a3); a3 = fmaf(wreg[3][kk].w, hv.w, a3);
        }
        a0 += __shfl_xor(a0, 8, 64); a0 += __shfl_xor(a0, 16, 64); a0 += __shfl_xor(a0, 32, 64);
        a1 += __shfl_xor(a1, 8, 64); a1 += __shfl_xor(a1, 16, 64); a1 += __shfl_xor(a1, 32, 64);
        a2 += __shfl_xor(a2, 8, 64); a2 += __shfl_xor(a2, 16, 64); a2 += __shfl_xor(a2, 32, 64);
        a3 += __shfl_xor(a3, 8, 64); a3 += __shfl_xor(a3, 16, 64); a3 += __shfl_xor(a3, 32, 64);

        if (tl > 0) {
            // ---- spin-sum step t-1's score; resolve pred + out (overlapped) --
            float s0 = 0.f, s1 = 0.f;
#pragma unroll
            for (int wv = 0; wv < 8; ++wv) {
                unsigned long long v0, v1;
                do {
                    v0 = __hip_atomic_load(&redL[wv][0],
                                           __ATOMIC_RELAXED, __HIP_MEMORY_SCOPE_WORKGROUP);
                } while ((unsigned)v0 != cnt);
                do {
                    v1 = __hip_atomic_load(&redL[wv][1],
                                           __ATOMIC_RELAXED, __HIP_MEMORY_SCOPE_WORKGROUP);
                } while ((unsigned)v1 != cnt);
                s0 += __uint_as_float((unsigned)(v0 >> 32));
                s1 += __uint_as_float((unsigned)(v1 >> 32));
            }
            float ts0 = s0 + psv0, ts1 = s1 + psv1;
            pred = (ts1 > ts0) ? 1 : 0;
            if (g == 0 && tid == 0) {
                float m = fmaxf(ts0, ts1);
                float lse = m + log1pf(expf(-fabsf(ts0 - ts1)));
                float* op = out + ((size_t)b * TT + (t - 1)) * 2;
                op[0] = ts0 - lse; op[1] = ts1 - lse;
            }
        }

        // ---- gates ----
        float pv0 = 0.f, pv1 = 0.f, pv2 = 0.f, pv3 = 0.f;
        if (pred >= 0) {
            pv0 = P[pred][0][jh]; pv1 = P[pred][1][jh];
            pv2 = P[pred][2][jh]; pv3 = P[pred][3][jh];
        }
        float gi = a0 + cgp0 + pv0;
        float gf = a1 + cgp1 + pv1;
        float gg = a2 + cgp2 + pv2;
        float go = a3 + cgp3 + pv3;
        float ig = sigf(gi), fg = sigf(gf);
        float g2 = tanhfast(gg), og = sigf(go);
        float cn = fmaf(fg, creg, ig * g2);
        float hn = og * tanhfast(cn);
        creg = cn * cmi + creg * (1.f - cmi);

        // ---- publish own slice ----
        if (kq == 0) {
            unsigned long long wd =
                ((unsigned long long)__float_as_uint(hn) << 32) | cnt;
            __hip_atomic_store(&hbox[((size_t)(p * BB + b) * 4 + g) * 64 + jh], wd,
                               __ATOMIC_RELAXED, __HIP_MEMORY_SCOPE_AGENT);
            hnS[p][jglob] = hn;
        }

        // ---- prefetch next step's operands (hidden under the polls) ----
        float ngp0 = 0.f, ngp1 = 0.f, ngp2 = 0.f, ngp3 = 0.f;
        float nmi = 0.f, ns0 = 0.f, ns1 = 0.f;
        if (tl + 1 < Tc) {
            const float* gp2 = gpre + ((size_t)(tl + 1) * BB + b) * NG;
            ngp0 = gp2[0 * HH + jglob]; ngp1 = gp2[1 * HH + jglob];
            ngp2 = gp2[2 * HH + jglob]; ngp3 = gp2[3 * HH + jglob];
            nmi = mask[(size_t)b * TT + t + 1];
            const float* s2n = shi + ((size_t)(tl + 1) * BB + b) * 2;
            ns0 = s2n[0]; ns1 = s2n[1];
        }

        // ---- gather partner slices ----
        if (tid < 192) {
            int pg = (g + 1 + (tid >> 6)) & 3, j2 = tid & 63;
            const unsigned long long* wp =
                &hbox[((size_t)(p * BB + b) * 4 + pg) * 64 + j2];
            unsigned long long wv;
            do {
                wv = __hip_atomic_load(wp, __ATOMIC_RELAXED, __HIP_MEMORY_SCOPE_AGENT);
            } while ((unsigned)wv != cnt);
            hnS[p][pg * 64 + j2] = __uint_as_float((unsigned)(wv >> 32));
        }
        __syncthreads();   // B3: hnS[p] complete

        // carry step-t values for next iteration's mix/score
        pmi = cmi; psv0 = cs0; psv1 = cs1;
        cgp0 = ngp0; cgp1 = ngp1; cgp2 = ngp2; cgp3 = ngp3;
        cmi = nmi; cs0 = ns0; cs1 = ns1;
    }

    // ---- epilogue: final mix + final score/out + state stores ----
    {
        const int pl = (t0 + Tc - 1) & 1;
        const unsigned fcnt = (unsigned)(t0 + Tc + 1);
        const float4* hp = (const float4*)(&hnS[pl][kq * 32]);
#pragma unroll
        for (int i = 0; i < 8; ++i) {
            float4 hv = hp[i];
            hoct[i].x = hv.x * pmi + hoct[i].x * (1.f - pmi);
            hoct[i].y = hv.y * pmi + hoct[i].y * (1.f - pmi);
            hoct[i].z = hv.z * pmi + hoct[i].z * (1.f - pmi);
            hoct[i].w = hv.w * pmi + hoct[i].w * (1.f - pmi);
        }
        float pr = hnS[pl][sdim] * waffR;
        pr += __shfl_xor(pr, 1, 64);
        pr += __shfl_xor(pr, 2, 64);
        pr += __shfl_xor(pr, 4, 64);
        pr += __shfl_xor(pr, 8, 64);
        pr += __shfl_xor(pr, 16, 64);
        if ((lane & 31) == 0) {
            unsigned long long wd =
                ((unsigned long long)__float_as_uint(pr) << 32) | fcnt;
            __hip_atomic_store(&redL[w][stag], wd,
                               __ATOMIC_RELAXED, __HIP_MEMORY_SCOPE_WORKGROUP);
        }
        float s0 = 0.f, s1 = 0.f;
#pragma unroll
        for (int wv = 0; wv < 8; ++wv) {
            unsigned long long v0, v1;
            do {
                v0 = __hip_atomic_load(&redL[wv][0],
                                       __ATOMIC_RELAXED, __HIP_MEMORY_SCOPE_WORKGROUP);
            } while ((unsigned)v0 != fcnt);
            do {
                v1 = __hip_atomic_load(&redL[wv][1],
                                       __ATOMIC_RELAXED, __HIP_MEMORY_SCOPE_WORKGROUP);
            } while ((unsigned)v1 != fcnt);
            s0 += __uint_as_float((unsigned)(v0 >> 32));
            s1 += __uint_as_float((unsigned)(v1 >> 32));
        }
        float ts0 = s0 + psv0, ts1 = s1 + psv1;
        pred = (ts1 > ts0) ? 1 : 0;
        if (g == 0 && tid == 0) {
            float m = fmaxf(ts0, ts1);
            float lse = m + log1pf(expf(-fabsf(ts0 - ts1)));
            float* op = out + ((size_t)b * TT + (t0 + Tc - 1)) * 2;
            op[0] = ts0 - lse; op[1] = ts1 - lse;
        }
    }
    if (w == 0 && jl == 0) {   // lanes 0,8,..,56 of wave 0: one per octant
        float4* dst = (float4*)(sh + (size_t)b * HH + kq * 32);
#pragma unroll
        for (int i = 0; i < 8; ++i) dst[i] = hoct[i];
    }
    if (kq == 0) sc[(size_t)b * HH + jglob] = creg;
    if (g == 0 && tid == 0) sp[b] = pred;
}

// ---------------------------------------------------------------------------
extern "C" void kernel_launch(void* const* d_in, const int* in_sizes, int n_in,
                              void* d_out, int out_size, void* d_ws, size_t ws_size,
                              hipStream_t stream) {
    (void)in_sizes; (void)n_in; (void)out_size;
    const float* sents = (const float*)d_in[0];
    const float* mask  = (const float*)d_in[1];
    const float* Wih   = (const float*)d_in[2];
    const float* Whh   = (const float*)d_in[3];
    const float* bih   = (const float*)d_in[4];
    const float* bhh   = (const float*)d_in[5];
    const float* Waff  = (const float*)d_in[6];
    const float* baff  = (const float*)d_in[7];
    const float* tag   = (const float*)d_in[8];
    float* out = (float*)d_out;

    const size_t wsplit = (size_t)NG * DI * 2 * 2;        // WH + WL (3 MB)
    const size_t fixed = wsplit
                       + (size_t)BB * HH * 4 * 2          // sh, sc
                       + BB * 4                            // sp
                       + (size_t)2 * BB * 4 * 64 * 8      // hbox
                       + 4096;
    int Tc = 8;
    const int cands[7] = {512, 256, 128, 64, 32, 16, 8};
    for (int i = 0; i < 7; ++i) {
        size_t need = (size_t)cands[i] * BB * NG * 4
                    + (size_t)cands[i] * BB * 2 * 4
                    + fixed;
        if (need <= ws_size) { Tc = cands[i]; break; }
    }

    char* wsp = (char*)d_ws;
    unsigned short* WH = (unsigned short*)wsp; wsp += (size_t)NG * DI * 2;
    unsigned short* WL = (unsigned short*)wsp; wsp += (size_t)NG * DI * 2;
    float* gpre = (float*)wsp; wsp += (size_t)Tc * BB * NG * 4;
    float* shiw = (float*)wsp; wsp += (size_t)Tc * BB * 2 * 4;
    float* shst = (float*)wsp; wsp += (size_t)BB * HH * 4;
    float* scst = (float*)wsp; wsp += (size_t)BB * HH * 4;
    int*   spst = (int*)wsp;   wsp += BB * 4;
    unsigned long long* hbox = (unsigned long long*)wsp;

    kconvW<<<dim3(3, 1024), 256, 0, stream>>>(Wih, WH, WL);
    kinit<<<dim3(64), 512, 0, stream>>>(hbox);

    const int nch = TT / Tc;
    for (int c = 0; c < nch; ++c) {
        const int t0 = c * Tc;
        kgemm2<<<dim3(8, Tc * 64 / 128), 256, 0, stream>>>(sents, WH, WL, bih, bhh, gpre, t0);
        kshi<<<dim3(Tc * 16), 256, 0, stream>>>(sents, Waff, baff, shiw, t0);
        krec6<<<dim3(256), 512, 0, stream>>>(gpre, shiw, Whh, mask, out,
                                             shst, scst, spst, hbox,
                                             Wih, tag, Waff, t0, Tc, (c == 0) ? 1 : 0);
    }
}